// Round 4
// baseline (299.045 us; speedup 1.0000x reference)
//
#include <hip/hip_runtime.h>

// ---------------------------------------------------------------------------
// LSTM (Alex Graves) single step, batch 8192 — fused GEMM+epilogue, r4.
// Structure change: "W-resident" GEMM with NO barriers in the K-loop.
//   - block = 1024 thr (16 waves) = 64 gate-permuted cols x 1024 rows
//   - W slice (64 x 768 fp16) lives in LDS, loaded in two 48 KB K-halves
//     (2 barriers per kernel total vs 12 vmcnt(0) drains in the r3 m97-style
//     loop — the documented ~20% plateau stall)
//   - A fragments read global->register (16B/lane, L2-hit after XCD swizzle)
//   - grid = 256 = 1 block/CU; fid&7 = row-group -> each XCD's 32 blocks
//     share one 1.5 MB A slice (L2-resident)
//   W rows permuted: row c = gate g=(c>>4)&3, unit jj=((c>>6)<<4)|(c&15)
//     -> register j = gate, lane&15 = jj: epilogue entirely in registers.
//   out[0:8192*512) = cm ; out[8192*512:) = h
// ---------------------------------------------------------------------------

typedef _Float16 half8 __attribute__((ext_vector_type(8)));
typedef _Float16 half4v __attribute__((ext_vector_type(4)));
typedef float floatx4 __attribute__((ext_vector_type(4)));

#define BATCH 8192
#define NSTEPS 16
#define IN_F 256
#define OUT_F 512
#define KDIM 768    // OUT_F + IN_F
#define NDIM 2048   // 4 * OUT_F
#define HSIZE ((size_t)BATCH * OUT_F)

// W-resident GEMM geometry
#define COLS 64          // cols per block (16 units x 4 gates)
#define ROWS_BLK 1024    // rows per block (16 waves x 64)
#define KHALF 384        // K per LDS pass
#define KC_PASS 48       // 16B chunks per col per pass (384*2/16)

__device__ __forceinline__ void async_copy16(const void* gptr, void* lptr) {
  __builtin_amdgcn_global_load_lds(
      (const __attribute__((address_space(1))) unsigned int*)gptr,
      (__attribute__((address_space(3))) unsigned int*)lptr,
      16, 0, 0);
}

__device__ __forceinline__ float sigmoidf_(float x) {
  return 1.0f / (1.0f + __expf(-x));
}

__device__ __forceinline__ float tanhf_(float x) {
  x = fminf(fmaxf(x, -20.0f), 20.0f);   // __expf(|2x|>~176) would inf->NaN
  float e = __expf(2.0f * x);
  return (e - 1.0f) / (e + 1.0f);
}

// ------------------- merged pack: A rows then W rows -----------------------
// blocks [0,8192): A row b = [H[b] | x[b,n]] ; blocks [8192,10240): W row.
// W permuted rows: c -> gate g=(c>>4)&3, unit jj=((c>>6)<<4)|(c&15);
// cols [0,512)=w_h row jj of gate g ; [512,768)=w_x row jj.
__global__ void pack_AW(const float* __restrict__ H, const float* __restrict__ x,
                        const int* __restrict__ nptr,
                        const float* __restrict__ fg_w_h, const float* __restrict__ fg_w_x,
                        const float* __restrict__ ig_w_h, const float* __restrict__ ig_w_x,
                        const float* __restrict__ in_w_h, const float* __restrict__ in_w_x,
                        const float* __restrict__ og_w_h, const float* __restrict__ og_w_x,
                        _Float16* __restrict__ A, _Float16* __restrict__ W) {
  const int blk = blockIdx.x;
  const int k = threadIdx.x * 4;
  const float* src;
  _Float16* dst;
  if (blk < BATCH) {
    const int b = blk;
    if (k < OUT_F) {
      src = H + (size_t)b * OUT_F + k;
    } else {
      const int n = *nptr;
      src = x + ((size_t)b * NSTEPS + n) * IN_F + (k - OUT_F);
    }
    dst = A + (size_t)b * KDIM + k;
  } else {
    const int row = blk - BATCH;
    const int g  = (row >> 4) & 3;
    const int jj = ((row >> 6) << 4) | (row & 15);
    if (k < OUT_F) {
      const float* wh = (g == 0) ? fg_w_h : (g == 1) ? ig_w_h : (g == 2) ? in_w_h : og_w_h;
      src = wh + (size_t)jj * OUT_F + k;
    } else {
      const float* wx = (g == 0) ? fg_w_x : (g == 1) ? ig_w_x : (g == 2) ? in_w_x : og_w_x;
      src = wx + (size_t)jj * IN_F + (k - OUT_F);
    }
    dst = W + (size_t)row * KDIM + k;
  }
  float4 v = *(const float4*)src;
  half4v h = {(_Float16)v.x, (_Float16)v.y, (_Float16)v.z, (_Float16)v.w};
  *(half4v*)dst = h;
}

// ---------------- W-resident fused GEMM + gate epilogue --------------------
// LDS: Ws granule slot s = col*48 + kc_lds holds global chunk
// kc_glb = kc_lds ^ (col&7)  (16B granules; same 2-way-free swizzle family
// as the verified r3 kernel, and global_load_lds dst stays uniform+lane*16).
__global__ __launch_bounds__(1024, 4) void gemm_lstm(
    const _Float16* __restrict__ A, const _Float16* __restrict__ W,
    const float* __restrict__ C,
    const float* __restrict__ fg_w_c, const float* __restrict__ fg_b,
    const float* __restrict__ ig_w_c, const float* __restrict__ ig_b,
    const float* __restrict__ in_b,
    const float* __restrict__ og_w_cn, const float* __restrict__ og_b,
    float* __restrict__ out) {
  __shared__ __align__(16) _Float16 Ws[COLS * KC_PASS * 8];  // 48 KB

  const int tid = threadIdx.x;
  const int lane = tid & 63;
  const int wave = tid >> 6;        // 0..15
  const int quad = lane >> 4;
  const int l16 = lane & 15;

  const int fid = blockIdx.x;       // 256 blocks
  const int rg   = fid & 7;         // row group -> XCD (L2 locality for A)
  const int colb = fid >> 3;        // 0..31
  const int n0 = colb * COLS;
  const int mw = rg * ROWS_BLK + wave * 64;   // this wave's 64-row strip

  // this lane's output unit
  const int jj = (colb << 4) | l16;
  const float fwc = fg_w_c[jj], fb = fg_b[jj];
  const float iwc = ig_w_c[jj], ib = ig_b[jj];
  const float nb  = in_b[jj];
  const float owc = og_w_cn[jj], ob = og_b[jj];

  const _Float16* Abase = A + (size_t)mw * KDIM;

  floatx4 acc[4][4] = {};

#pragma unroll
  for (int kh = 0; kh < 2; ++kh) {
    __syncthreads();                // pass-1 reads done before overwrite
#pragma unroll
    for (int it = 0; it < 3; ++it) {
      const int s = it * 1024 + tid;            // granule slot 0..3071
      const int col = s / KC_PASS;
      const int kc = s - col * KC_PASS;
      const int kcg = kc ^ (col & 7);           // swizzled global chunk
      async_copy16(W + (size_t)(n0 + col) * KDIM + kh * KHALF + kcg * 8,
                   (_Float16*)Ws + s * 8);
    }
    __syncthreads();

    for (int ks = 0; ks < 12; ++ks) {           // 12 x K=32, NO barriers
      const int kbase = kh * KHALF + ks * 32 + quad * 8;
      half8 af[4], bf[4];
#pragma unroll
      for (int i = 0; i < 4; ++i)
        af[i] = *(const half8*)(Abase + (size_t)(i * 16 + l16) * KDIM + kbase);
#pragma unroll
      for (int j = 0; j < 4; ++j) {
        const int cl = j * 16 + l16;
        const int kc = (ks * 4 + quad) ^ (cl & 7);
        bf[j] = *(const half8*)(Ws + (cl * KC_PASS + kc) * 8);
      }
#pragma unroll
      for (int i = 0; i < 4; ++i)
#pragma unroll
        for (int j = 0; j < 4; ++j)
          acc[i][j] = __builtin_amdgcn_mfma_f32_16x16x32_f16(af[i], bf[j], acc[i][j], 0, 0, 0);
    }
  }

  // ---- epilogue in registers. C/D: col=lane&15 (=jj), row=quad*4+r ----
  float cv[16];
#pragma unroll
  for (int i = 0; i < 4; ++i) {
    const int rbase = mw + i * 16 + quad * 4;
#pragma unroll
    for (int r = 0; r < 4; ++r)
      cv[i * 4 + r] = C[(size_t)(rbase + r) * OUT_F + jj];
  }
  float inn[16];
#pragma unroll
  for (int i = 0; i < 4; ++i)
#pragma unroll
    for (int r = 0; r < 4; ++r)
      inn[i * 4 + r] = tanhf_(acc[i][2][r] + nb);
#pragma unroll
  for (int i = 0; i < 4; ++i) {
    const int rbase = mw + i * 16 + quad * 4;
#pragma unroll
    for (int r = 0; r < 4; ++r) {
      const int b = rbase + r;
      const float c = cv[i * 4 + r];
      const float fg  = sigmoidf_(fwc * c + acc[i][0][r] + fb);
      const float ig  = sigmoidf_(iwc * c + acc[i][1][r] + ib);
      const float cm  = fg * c + ig * inn[i * 4 + r];
      const float og  = sigmoidf_(owc * cm + acc[i][3][r] + ob);
      out[(size_t)b * OUT_F + jj] = cm;
      out[HSIZE + (size_t)b * OUT_F + jj] = og * tanhf_(cm);
    }
  }
}

// ---------------------------------------------------------------------------
extern "C" void kernel_launch(void* const* d_in, const int* in_sizes, int n_in,
                              void* d_out, int out_size, void* d_ws, size_t ws_size,
                              hipStream_t stream) {
  const float* x       = (const float*)d_in[0];
  const float* C       = (const float*)d_in[1];
  const float* H       = (const float*)d_in[2];
  const float* fg_w_c  = (const float*)d_in[3];
  const float* fg_w_h  = (const float*)d_in[4];
  const float* fg_w_x  = (const float*)d_in[5];
  const float* fg_b    = (const float*)d_in[6];
  const float* ig_w_c  = (const float*)d_in[7];
  const float* ig_w_h  = (const float*)d_in[8];
  const float* ig_w_x  = (const float*)d_in[9];
  const float* ig_b    = (const float*)d_in[10];
  const float* in_w_h  = (const float*)d_in[11];
  const float* in_w_x  = (const float*)d_in[12];
  const float* in_b    = (const float*)d_in[13];
  const float* og_w_cn = (const float*)d_in[14];
  const float* og_w_h  = (const float*)d_in[15];
  const float* og_w_x  = (const float*)d_in[16];
  const float* og_b    = (const float*)d_in[17];
  const int*   nptr    = (const int*)d_in[18];

  char* ws = (char*)d_ws;
  _Float16* Apk = (_Float16*)ws;                // 8192*768*2 = 12,582,912 B
  _Float16* Wpk = (_Float16*)(ws + 12582912);   // 2048*768*2 =  3,145,728 B
  (void)ws_size; (void)in_sizes; (void)n_in; (void)out_size;

  pack_AW<<<BATCH + NDIM, 192, 0, stream>>>(H, x, nptr,
                                            fg_w_h, fg_w_x, ig_w_h, ig_w_x,
                                            in_w_h, in_w_x, og_w_h, og_w_x,
                                            Apk, Wpk);
  gemm_lstm<<<256, 1024, 0, stream>>>(Apk, Wpk, C,
                                      fg_w_c, fg_b, ig_w_c, ig_b, in_b,
                                      og_w_cn, og_b, (float*)d_out);
}

// Round 5
// 253.953 us; speedup vs baseline: 1.1776x; 1.1776x over previous
//
#include <hip/hip_runtime.h>

// ---------------------------------------------------------------------------
// LSTM (Alex Graves) single step, batch 8192 — fused GEMM+epilogue, r5.
// r3 structure (m97-style 128x128 tile GEMM, known-good) + LDS-staged
// coalesced output stores (r4 counters showed WRITE_SIZE 2.8x amplification
// from 64B-segment scattered stores at 128B HBM granularity).
//   A = [H | x[:,n,:]]  (8192 x 768)  fp16-packed
//   W rows permuted:  row c = gate g=(c>>4)&3, unit jj=((c>>6)<<4)|(c&15)
//     -> register j = gate, lane&15 = jj: epilogue entirely in registers.
//   out[0:8192*512) = cm ; out[8192*512:) = h
// ---------------------------------------------------------------------------

typedef _Float16 half8 __attribute__((ext_vector_type(8)));
typedef _Float16 half4v __attribute__((ext_vector_type(4)));
typedef float floatx4 __attribute__((ext_vector_type(4)));

#define BATCH 8192
#define NSTEPS 16
#define IN_F 256
#define OUT_F 512
#define KDIM 768    // OUT_F + IN_F
#define NDIM 2048   // 4 * OUT_F
#define HSIZE ((size_t)BATCH * OUT_F)

#define BM 128
#define BN 128
#define BK 64

__device__ __forceinline__ void async_copy16(const void* gptr, void* lptr) {
  __builtin_amdgcn_global_load_lds(
      (const __attribute__((address_space(1))) unsigned int*)gptr,
      (__attribute__((address_space(3))) unsigned int*)lptr,
      16, 0, 0);
}

__device__ __forceinline__ float sigmoidf_(float x) {
  return 1.0f / (1.0f + __expf(-x));
}

__device__ __forceinline__ float tanhf_(float x) {
  x = fminf(fmaxf(x, -20.0f), 20.0f);   // __expf(|2x|>~176) would inf->NaN
  float e = __expf(2.0f * x);
  return (e - 1.0f) / (e + 1.0f);
}

// ------------------- merged pack: A rows then W rows -----------------------
__global__ void pack_AW(const float* __restrict__ H, const float* __restrict__ x,
                        const int* __restrict__ nptr,
                        const float* __restrict__ fg_w_h, const float* __restrict__ fg_w_x,
                        const float* __restrict__ ig_w_h, const float* __restrict__ ig_w_x,
                        const float* __restrict__ in_w_h, const float* __restrict__ in_w_x,
                        const float* __restrict__ og_w_h, const float* __restrict__ og_w_x,
                        _Float16* __restrict__ A, _Float16* __restrict__ W) {
  const int blk = blockIdx.x;
  const int k = threadIdx.x * 4;
  const float* src;
  _Float16* dst;
  if (blk < BATCH) {
    const int b = blk;
    if (k < OUT_F) {
      src = H + (size_t)b * OUT_F + k;
    } else {
      const int n = *nptr;
      src = x + ((size_t)b * NSTEPS + n) * IN_F + (k - OUT_F);
    }
    dst = A + (size_t)b * KDIM + k;
  } else {
    const int row = blk - BATCH;
    const int g  = (row >> 4) & 3;
    const int jj = ((row >> 6) << 4) | (row & 15);
    if (k < OUT_F) {
      const float* wh = (g == 0) ? fg_w_h : (g == 1) ? ig_w_h : (g == 2) ? in_w_h : og_w_h;
      src = wh + (size_t)jj * OUT_F + k;
    } else {
      const float* wx = (g == 0) ? fg_w_x : (g == 1) ? ig_w_x : (g == 2) ? in_w_x : og_w_x;
      src = wx + (size_t)jj * IN_F + (k - OUT_F);
    }
    dst = W + (size_t)row * KDIM + k;
  }
  float4 v = *(const float4*)src;
  half4v h = {(_Float16)v.x, (_Float16)v.y, (_Float16)v.z, (_Float16)v.w};
  *(half4v*)dst = h;
}

// ---------------------- fused GEMM + gate epilogue -------------------------
// 128x128 tile, BK=64, 256 thr / 4 waves, each wave 64x64 (4x4 MFMA tiles).
// LDS 16B-granule XOR swizzle applied on the GLOBAL address side.
// Block's output region: rows m0..m0+127, units jj in [bx*32, bx*32+32):
// 128 B per row per tile -> full-line coalesced stores after LDS transpose.
__global__ __launch_bounds__(256, 4) void gemm_lstm(
    const _Float16* __restrict__ A, const _Float16* __restrict__ W,
    const float* __restrict__ C,
    const float* __restrict__ fg_w_c, const float* __restrict__ fg_b,
    const float* __restrict__ ig_w_c, const float* __restrict__ ig_b,
    const float* __restrict__ in_b,
    const float* __restrict__ og_w_cn, const float* __restrict__ og_b,
    float* __restrict__ out) {
  __shared__ __align__(16) char smem[32768];
  _Float16* As = (_Float16*)smem;            // 16 KB (K-loop)
  _Float16* Bs = (_Float16*)(smem + 16384);  // 16 KB (K-loop)
  float* cmS = (float*)smem;                 // 16 KB (epilogue, 128x32)
  float* hS  = (float*)(smem + 16384);       // 16 KB (epilogue, 128x32)

  const int tid = threadIdx.x;
  const int lane = tid & 63;
  const int wave = tid >> 6;
  const int quad = lane >> 4;
  const int l16 = lane & 15;
  const int m0 = blockIdx.y * BM;
  const int n0 = blockIdx.x * BN;
  const int mw = (wave >> 1) * 64;
  const int nw = (wave & 1) * 64;

  // this lane's output unit
  const int jj = (((n0 + nw) >> 6) << 4) | l16;
  const float fwc = fg_w_c[jj], fb = fg_b[jj];
  const float iwc = ig_w_c[jj], ib = ig_b[jj];
  const float nb  = in_b[jj];
  const float owc = og_w_cn[jj], ob = og_b[jj];

  floatx4 acc[4][4] = {};

  for (int kt = 0; kt < KDIM; kt += BK) {
    __syncthreads();
#pragma unroll
    for (int r = 0; r < 4; ++r) {
      const int g = r * 256 + tid;       // 16B granule index
      const int row = g >> 3;
      const int cl = g & 7;
      const int cg = cl ^ (row & 7);     // swizzled global chunk
      async_copy16(A + (size_t)(m0 + row) * KDIM + kt + cg * 8,
                   As + g * 8);
      async_copy16(W + (size_t)(n0 + row) * KDIM + kt + cg * 8,
                   Bs + g * 8);
    }
    __syncthreads();

#pragma unroll
    for (int ks = 0; ks < 2; ++ks) {
      half8 af[4], bf[4];
#pragma unroll
      for (int i = 0; i < 4; ++i) {
        const int row = mw + i * 16 + l16;
        const int chunk = ks * 4 + quad;
        const int gran = row * 8 + (chunk ^ (row & 7));
        af[i] = *(const half8*)(As + gran * 8);
      }
#pragma unroll
      for (int j = 0; j < 4; ++j) {
        const int row = nw + j * 16 + l16;
        const int chunk = ks * 4 + quad;
        const int gran = row * 8 + (chunk ^ (row & 7));
        bf[j] = *(const half8*)(Bs + gran * 8);
      }
#pragma unroll
      for (int i = 0; i < 4; ++i)
#pragma unroll
        for (int j = 0; j < 4; ++j)
          acc[i][j] = __builtin_amdgcn_mfma_f32_16x16x32_f16(af[i], bf[j], acc[i][j], 0, 0, 0);
    }
  }

  // ---- epilogue. C/D: col=lane&15 (=jj lane), row=quad*4+r ----
  // batched C loads first (overlap their HBM latency with tanh below)
  float cv[16];
#pragma unroll
  for (int i = 0; i < 4; ++i) {
    const int rbase = m0 + mw + i * 16 + quad * 4;
#pragma unroll
    for (int r = 0; r < 4; ++r)
      cv[i * 4 + r] = C[(size_t)(rbase + r) * OUT_F + jj];
  }
  float inn[16];
#pragma unroll
  for (int i = 0; i < 4; ++i)
#pragma unroll
    for (int r = 0; r < 4; ++r)
      inn[i * 4 + r] = tanhf_(acc[i][2][r] + nb);

  __syncthreads();   // all K-loop ds_reads complete before As/Bs overwrite

  const int jjloc = (nw >> 6) * 16 + l16;      // 0..31 within block tile
#pragma unroll
  for (int i = 0; i < 4; ++i) {
    const int rloc0 = mw + i * 16 + quad * 4;  // block-local row 0..127
#pragma unroll
    for (int r = 0; r < 4; ++r) {
      const float c = cv[i * 4 + r];
      const float fg  = sigmoidf_(fwc * c + acc[i][0][r] + fb);
      const float ig  = sigmoidf_(iwc * c + acc[i][1][r] + ib);
      const float cm  = fg * c + ig * inn[i * 4 + r];
      const float og  = sigmoidf_(owc * cm + acc[i][3][r] + ob);
      cmS[(rloc0 + r) * 32 + jjloc] = cm;
      hS [(rloc0 + r) * 32 + jjloc] = og * tanhf_(cm);
    }
  }
  __syncthreads();

  // cooperative coalesced store: 128 rows x 32 cols per tile; thread q-loop
  // covers 4 float4 each; wave = 8 rows x 128 B contiguous per instruction.
  const int bx32 = blockIdx.x * 32;
#pragma unroll
  for (int q = 0; q < 4; ++q) {
    const int idx = q * 256 + tid;
    const int row = idx >> 3;
    const int c4 = idx & 7;
    const size_t gbase = (size_t)(m0 + row) * OUT_F + bx32 + c4 * 4;
    *(float4*)(out + gbase) = *(const float4*)(cmS + row * 32 + c4 * 4);
    *(float4*)(out + HSIZE + gbase) = *(const float4*)(hS + row * 32 + c4 * 4);
  }
}

// ---------------------------------------------------------------------------
extern "C" void kernel_launch(void* const* d_in, const int* in_sizes, int n_in,
                              void* d_out, int out_size, void* d_ws, size_t ws_size,
                              hipStream_t stream) {
  const float* x       = (const float*)d_in[0];
  const float* C       = (const float*)d_in[1];
  const float* H       = (const float*)d_in[2];
  const float* fg_w_c  = (const float*)d_in[3];
  const float* fg_w_h  = (const float*)d_in[4];
  const float* fg_w_x  = (const float*)d_in[5];
  const float* fg_b    = (const float*)d_in[6];
  const float* ig_w_c  = (const float*)d_in[7];
  const float* ig_w_h  = (const float*)d_in[8];
  const float* ig_w_x  = (const float*)d_in[9];
  const float* ig_b    = (const float*)d_in[10];
  const float* in_w_h  = (const float*)d_in[11];
  const float* in_w_x  = (const float*)d_in[12];
  const float* in_b    = (const float*)d_in[13];
  const float* og_w_cn = (const float*)d_in[14];
  const float* og_w_h  = (const float*)d_in[15];
  const float* og_w_x  = (const float*)d_in[16];
  const float* og_b    = (const float*)d_in[17];
  const int*   nptr    = (const int*)d_in[18];

  char* ws = (char*)d_ws;
  _Float16* Apk = (_Float16*)ws;                // 8192*768*2 = 12,582,912 B
  _Float16* Wpk = (_Float16*)(ws + 12582912);   // 2048*768*2 =  3,145,728 B
  (void)ws_size; (void)in_sizes; (void)n_in; (void)out_size;

  pack_AW<<<BATCH + NDIM, 192, 0, stream>>>(H, x, nptr,
                                            fg_w_h, fg_w_x, ig_w_h, ig_w_x,
                                            in_w_h, in_w_x, og_w_h, og_w_x,
                                            Apk, Wpk);
  dim3 grid(NDIM / BN, BATCH / BM);  // (16, 64) = 1024 blocks = 4/CU
  gemm_lstm<<<grid, 256, 0, stream>>>(Apk, Wpk, C,
                                      fg_w_c, fg_b, ig_w_c, ig_b, in_b,
                                      og_w_cn, og_b, (float*)d_out);
}